// Round 7
// baseline (103.831 us; speedup 1.0000x reference)
//
#include <hip/hip_runtime.h>
#include <math.h>

static constexpr int BATCH = 32;
static constexpr int SEQ   = 4096;
static constexpr int HID   = 1024;
static constexpr int PSTRIDE = HID + 8;   // ctx[1024] + m + l (+pad, keeps 16B alignment)

typedef float f32x4 __attribute__((ext_vector_type(4)));   // native vector: OK for nontemporal builtins

// -------- Pass 1: fused scores + online-softmax context partials --------
// grid = BATCH*NCHUNK blocks, 256 threads (4 waves).
// R6 known-good structure (97.5us): manual 2-row unroll, treed dots,
// interleaved shfl chains, nontemporal enc loads.
// R7 delta: NCHUNK 32 -> 64. Resources allow ~6 blocks/CU (VGPR ~84,
// LDS 20.9KB) but a 1024-block grid only put 4/CU; 2048 blocks raises
// resident waves 16 -> 24/CU to keep more loads outstanding.
template<int NCHUNK>
__global__ __launch_bounds__(256, 4)
void attn_fused_pass1(const float* __restrict__ enc,
                      const float* __restrict__ dec,
                      float* __restrict__ raw_scores,   // [B,S] = weights region of d_out
                      float* __restrict__ partials)     // [B*NCHUNK][PSTRIDE]
{
    constexpr int RC  = SEQ / NCHUNK;   // rows per chunk
    constexpr int RPW = RC / 4;         // rows per wave
    const int b     = blockIdx.x / NCHUNK;
    const int chunk = blockIdx.x % NCHUNK;
    const int tid   = threadIdx.x;
    const int w     = tid >> 6;
    const int lane  = tid & 63;

    __shared__ float s_dec[HID];
    __shared__ float s_ctx[4][HID];
    __shared__ float s_m[4], s_l[4];

    // stage dec[b] (4 KB) then keep this lane's 16-float fragment in registers
    ((float4*)s_dec)[tid] = ((const float4*)(dec + (size_t)b * HID))[tid];
    __syncthreads();
    const f32x4* sd = (const f32x4*)s_dec;
    const f32x4 d0 = sd[lane], d1 = sd[lane + 64], d2 = sd[lane + 128], d3 = sd[lane + 192];

    float m = -INFINITY, l = 0.f;
    f32x4 c0 = (f32x4)(0.f);
    f32x4 c1 = c0, c2 = c0, c3 = c0;

    const int row0 = chunk * RC + w * RPW;
    const f32x4* base = (const f32x4*)(enc + ((size_t)b * SEQ + row0) * HID);
    float* sout = raw_scores + (size_t)b * SEQ + row0;

    for (int r = 0; r < RPW; r += 2) {
        const f32x4* rpA = base + (size_t)r * (HID / 4);
        const f32x4* rpB = rpA + (HID / 4);
        const f32x4 a0 = __builtin_nontemporal_load(rpA + lane);
        const f32x4 a1 = __builtin_nontemporal_load(rpA + lane + 64);
        const f32x4 a2 = __builtin_nontemporal_load(rpA + lane + 128);
        const f32x4 a3 = __builtin_nontemporal_load(rpA + lane + 192);
        const f32x4 b0 = __builtin_nontemporal_load(rpB + lane);
        const f32x4 b1 = __builtin_nontemporal_load(rpB + lane + 64);
        const f32x4 b2 = __builtin_nontemporal_load(rpB + lane + 128);
        const f32x4 b3 = __builtin_nontemporal_load(rpB + lane + 192);

        // treed dot partials: 4 independent 4-FMA chains each, then 2 adds
        float tA0 = a0.x*d0.x + a0.y*d0.y + a0.z*d0.z + a0.w*d0.w;
        float tA1 = a1.x*d1.x + a1.y*d1.y + a1.z*d1.z + a1.w*d1.w;
        float tA2 = a2.x*d2.x + a2.y*d2.y + a2.z*d2.z + a2.w*d2.w;
        float tA3 = a3.x*d3.x + a3.y*d3.y + a3.z*d3.z + a3.w*d3.w;
        float tB0 = b0.x*d0.x + b0.y*d0.y + b0.z*d0.z + b0.w*d0.w;
        float tB1 = b1.x*d1.x + b1.y*d1.y + b1.z*d1.z + b1.w*d1.w;
        float tB2 = b2.x*d2.x + b2.y*d2.y + b2.z*d2.z + b2.w*d2.w;
        float tB3 = b3.x*d3.x + b3.y*d3.y + b3.z*d3.z + b3.w*d3.w;
        float tA = (tA0 + tA1) + (tA2 + tA3);
        float tB = (tB0 + tB1) + (tB2 + tB3);

        // two independent 6-step reduce chains, interleaved
        #pragma unroll
        for (int off = 32; off > 0; off >>= 1) {
            tA += __shfl_xor(tA, off, 64);
            tB += __shfl_xor(tB, off, 64);
        }

        if (lane == 0) {
            float2 sc2; sc2.x = tA; sc2.y = tB;
            *(float2*)(sout + r) = sc2;      // raw scores; normalized in pass 2
        }

        const float mn = fmaxf(m, fmaxf(tA, tB));
        if (mn > m) {                        // wave-uniform, rare after warm-up
            const float sc = __expf(m - mn); // m=-inf first time -> 0
            l *= sc;
            c0 *= sc; c1 *= sc; c2 *= sc; c3 *= sc;
            m = mn;
        }
        const float pA = __expf(tA - m);
        const float pB = __expf(tB - m);
        l += pA + pB;
        c0 += pA*a0 + pB*b0;
        c1 += pA*a1 + pB*b1;
        c2 += pA*a2 + pB*b2;
        c3 += pA*a3 + pB*b3;
    }

    // ---- combine the 4 waves of this block ----
    if (lane == 0) { s_m[w] = m; s_l[w] = l; }
    __syncthreads();
    const float mg = fmaxf(fmaxf(s_m[0], s_m[1]), fmaxf(s_m[2], s_m[3]));
    const float f  = __expf(m - mg);   // wave-uniform
    f32x4* sc4 = (f32x4*)s_ctx[w];
    sc4[lane]       = c0 * f;
    sc4[lane + 64]  = c1 * f;
    sc4[lane + 128] = c2 * f;
    sc4[lane + 192] = c3 * f;
    __syncthreads();

    float lb = 0.f;
    #pragma unroll
    for (int i = 0; i < 4; ++i) lb += s_l[i] * __expf(s_m[i] - mg);

    float* pout = partials + (size_t)(b * NCHUNK + chunk) * PSTRIDE;
    const f32x4 v0 = ((const f32x4*)s_ctx[0])[tid];
    const f32x4 v1 = ((const f32x4*)s_ctx[1])[tid];
    const f32x4 v2 = ((const f32x4*)s_ctx[2])[tid];
    const f32x4 v3 = ((const f32x4*)s_ctx[3])[tid];
    const f32x4 sum = (v0 + v1) + (v2 + v3);
    ((f32x4*)pout)[tid] = sum;
    if (tid == 0) { pout[HID] = mg; pout[HID + 1] = lb; }
}

// -------- Pass 2: cross-chunk combine + weights normalization --------
// grid = BATCH * 8 blocks; each block redundantly recomputes the cheap
// (m,l) combine; sub-block 0 writes context, all 8 split the weights row.
template<int NCHUNK>
__global__ __launch_bounds__(256)
void attn_pass2(const float* __restrict__ partials,
                float* __restrict__ out_ctx,    // [B,H]
                float* __restrict__ weights)    // [B,S] in-place raw->softmax
{
    const int b   = blockIdx.x >> 3;
    const int sub = blockIdx.x & 7;
    const int tid = threadIdx.x;
    __shared__ float sm[NCHUNK], sl[NCHUNK];
    if (tid < NCHUNK) {
        const float* p = partials + (size_t)(b * NCHUNK + tid) * PSTRIDE;
        sm[tid] = p[HID];
        sl[tid] = p[HID + 1];
    }
    __syncthreads();

    float mg = -INFINITY;
    #pragma unroll
    for (int c = 0; c < NCHUNK; ++c) mg = fmaxf(mg, sm[c]);
    float lg = 0.f;
    #pragma unroll
    for (int c = 0; c < NCHUNK; ++c) lg += sl[c] * __expf(sm[c] - mg);
    const float inv = 1.f / lg;

    if (sub == 0) {
        // context: one float4 per thread (H = 1024 = 256 float4)
        f32x4 acc = (f32x4)(0.f);
        #pragma unroll 4
        for (int c = 0; c < NCHUNK; ++c) {
            const f32x4* p4 = (const f32x4*)(partials + (size_t)(b * NCHUNK + c) * PSTRIDE);
            const float fc = __expf(sm[c] - mg);
            acc += fc * p4[tid];
        }
        acc *= inv;
        ((f32x4*)(out_ctx + (size_t)b * HID))[tid] = acc;
    }

    // weights: normalize raw scores in place, SEQ/8 = 512 per sub-block
    float* wrow = weights + (size_t)b * SEQ;
    const int s0 = sub * (SEQ / 8);
    #pragma unroll
    for (int i = 0; i < SEQ / 8 / 256; ++i) {
        const int s = s0 + i * 256 + tid;
        wrow[s] = __expf(wrow[s] - mg) * inv;
    }
}

extern "C" void kernel_launch(void* const* d_in, const int* in_sizes, int n_in,
                              void* d_out, int out_size, void* d_ws, size_t ws_size,
                              hipStream_t stream) {
    const float* hidden = (const float*)d_in[0];          // [2, 32, 1024]
    const float* enc    = (const float*)d_in[1];          // [32, 4096, 1024]
    const float* dec    = hidden + (size_t)BATCH * HID;   // hidden[-1] -> [32, 1024]

    float* out     = (float*)d_out;
    float* ctx_out = out;                                 // [32, 1024]
    float* w_out   = out + (size_t)BATCH * HID;           // [32, 4096]
    float* partials = (float*)d_ws;

#define LAUNCH_NC(NC)                                                              \
    do {                                                                           \
        attn_fused_pass1<NC><<<BATCH * NC, 256, 0, stream>>>(enc, dec, w_out,      \
                                                             partials);            \
        attn_pass2<NC><<<BATCH * 8, 256, 0, stream>>>(partials, ctx_out, w_out);   \
    } while (0)

    const size_t per_chunk_bytes = (size_t)BATCH * PSTRIDE * sizeof(float);
    if      (ws_size >= 64 * per_chunk_bytes) LAUNCH_NC(64);
    else if (ws_size >= 32 * per_chunk_bytes) LAUNCH_NC(32);
    else if (ws_size >= 16 * per_chunk_bytes) LAUNCH_NC(16);
    else if (ws_size >=  8 * per_chunk_bytes) LAUNCH_NC(8);
    else if (ws_size >=  4 * per_chunk_bytes) LAUNCH_NC(4);
    else if (ws_size >=  2 * per_chunk_bytes) LAUNCH_NC(2);
    else                                      LAUNCH_NC(1);
#undef LAUNCH_NC
}